// Round 6
// baseline (206.812 us; speedup 1.0000x reference)
//
#include <hip/hip_runtime.h>

#define NHID   512
#define NCLS   250
#define CHUNK  200
#define NTOK   2048
#define NOUT   450
#define NBLK   500             // 2 blocks per class (panels 0-6 / 7-12)
#define NTHR   256             // 4 waves
#define MAXTOK 64

typedef __attribute__((ext_vector_type(8))) short bf16x8;
typedef __attribute__((ext_vector_type(4))) float f32x4;

#define MFMA(a, b, c) __builtin_amdgcn_mfma_f32_16x16x32_bf16((a), (b), (c), 0, 0, 0)

__device__ __forceinline__ unsigned hpack(unsigned a, unsigned b) {
    return __builtin_amdgcn_perm(a, b, 0x07060302u);
}

// fp32x8 -> hi/lo split bf16x8 (truncate hi; lo = truncate(exact residual))
__device__ __forceinline__ void cvt8(float4 va, float4 vb, bf16x8& h, bf16x8& l) {
    unsigned u0 = __float_as_uint(va.x), u1 = __float_as_uint(va.y);
    unsigned u2 = __float_as_uint(va.z), u3 = __float_as_uint(va.w);
    unsigned u4 = __float_as_uint(vb.x), u5 = __float_as_uint(vb.y);
    unsigned u6 = __float_as_uint(vb.z), u7 = __float_as_uint(vb.w);
    union { unsigned w[4]; bf16x8 v; } H, L;
    H.w[0] = hpack(u1, u0); H.w[1] = hpack(u3, u2);
    H.w[2] = hpack(u5, u4); H.w[3] = hpack(u7, u6);
    float r0 = va.x - __uint_as_float(u0 & 0xffff0000u);
    float r1 = va.y - __uint_as_float(u1 & 0xffff0000u);
    float r2 = va.z - __uint_as_float(u2 & 0xffff0000u);
    float r3 = va.w - __uint_as_float(u3 & 0xffff0000u);
    float r4 = vb.x - __uint_as_float(u4 & 0xffff0000u);
    float r5 = vb.y - __uint_as_float(u5 & 0xffff0000u);
    float r6 = vb.z - __uint_as_float(u6 & 0xffff0000u);
    float r7 = vb.w - __uint_as_float(u7 & 0xffff0000u);
    L.w[0] = hpack(__float_as_uint(r1), __float_as_uint(r0));
    L.w[1] = hpack(__float_as_uint(r3), __float_as_uint(r2));
    L.w[2] = hpack(__float_as_uint(r5), __float_as_uint(r4));
    L.w[3] = hpack(__float_as_uint(r7), __float_as_uint(r6));
    h = H.v; l = L.v;
}

// one column-group (of 8) of a p_class unit, 2-deep register pipeline
__device__ __forceinline__ void class_unit(int u, int w8, int lane, int n, int q,
                                           const float* __restrict__ x,
                                           const float* __restrict__ Wc,
                                           const float* __restrict__ bc,
                                           float* __restrict__ out) {
    const int mt = u >> 1, hn = u & 1;
    const int g4 = (w8 >> 2) & 1, kk = w8 & 3;
    const int rC = (hn * 8 + g4 * 4 + kk) * 16 + n;
    const bool rv = rC < NCLS;
    const int  rc = rv ? rC : NCLS - 1;
    const float* ap = x  + (size_t)(mt * 16 + n) * NHID + q * 8;
    const float* bp = Wc + (size_t)rc * NHID + q * 8;
    const float bias = bc[rc];
    f32x4 acc = {0.f, 0.f, 0.f, 0.f};
    float4 qa[2][2], qb[2][2];
    #pragma unroll
    for (int j = 0; j < 2; ++j) {
        qa[j][0] = *(const float4*)(ap + j * 32);
        qa[j][1] = *(const float4*)(ap + j * 32 + 4);
        qb[j][0] = *(const float4*)(bp + j * 32);
        qb[j][1] = *(const float4*)(bp + j * 32 + 4);
    }
    #pragma unroll 2
    for (int s = 0; s < 16; ++s) {
        const int b = s & 1;
        bf16x8 ah, al, bh, bl;
        cvt8(qa[b][0], qa[b][1], ah, al);
        cvt8(qb[b][0], qb[b][1], bh, bl);
        acc = MFMA(ah, bh, acc);
        acc = MFMA(al, bh, acc);
        acc = MFMA(ah, bl, acc);
        if (s + 2 < 16) {
            qa[b][0] = *(const float4*)(ap + (s + 2) * 32);
            qa[b][1] = *(const float4*)(ap + (s + 2) * 32 + 4);
            qb[b][0] = *(const float4*)(bp + (s + 2) * 32);
            qb[b][1] = *(const float4*)(bp + (s + 2) * 32 + 4);
        }
    }
    if (rv) {
        #pragma unroll
        for (int i = 0; i < 4; ++i)
            out[(size_t)(mt * 16 + q * 4 + i) * NOUT + rc] = acc[i] + bias;
    }
}

__global__ __launch_bounds__(NTHR, 2)
void cbd_fused(const float* __restrict__ x,  const float* __restrict__ Wc,
               const float* __restrict__ bc, const float* __restrict__ Ww,
               const float* __restrict__ bw, const int* __restrict__ cls_idx,
               float* __restrict__ out)
{
    __shared__ short Afrag[16384];   // 16 tok x 16 ks x 4 q x (ah|al), 32 KB
    __shared__ int   toktmp[MAXTOK];

    const int tid  = threadIdx.x;
    const int wid  = tid >> 6;        // 0..3
    const int lane = tid & 63;
    const int n    = lane & 15;
    const int q    = lane >> 4;
    const int c    = blockIdx.x >> 1; // class
    const int h    = blockIdx.x & 1;  // panel half: 0 -> 0..6, 1 -> 7..12

    // ---- per-wave redundant token scan (identical values per wave) ----
    int myvals[32];
    #pragma unroll
    for (int it = 0; it < 8; ++it) {
        int4 v = *(const int4*)&cls_idx[it * 256 + lane * 4];
        myvals[it*4+0] = v.x; myvals[it*4+1] = v.y;
        myvals[it*4+2] = v.z; myvals[it*4+3] = v.w;
    }
    int cnt = 0;
    #pragma unroll
    for (int j = 0; j < 32; ++j) {
        int idx  = (j >> 2) * 256 + lane * 4 + (j & 3);
        bool hit = (myvals[j] == c);
        unsigned long long m = __ballot(hit);
        if (hit) {
            int pos = cnt + (int)__popcll(m & ((1ull << lane) - 1ull));
            if (pos < MAXTOK) toktmp[pos] = idx;
        }
        cnt += (int)__popcll(m);
    }
    const int cnt1 = cnt < 16 ? cnt : 16;

    int tkS[4]; bool msk[4];
    if (cnt) {
        int mytokA = toktmp[n < cnt1 ? n : cnt1 - 1];
        #pragma unroll
        for (int i = 0; i < 4; ++i) {
            tkS[i] = __shfl(mytokA, q * 4 + i);
            msk[i] = (q * 4 + i) < cnt1;
        }
        // ---- stage A once: split-bf16 fragments, XOR-swizzled slots ----
        // job = (tok, kstep, qslice): 1024 jobs over 256 threads.
        #pragma unroll
        for (int rep = 0; rep < 4; ++rep) {
            int job = rep * 256 + tid;
            int tok = job >> 6, s = (job >> 2) & 15, qq = job & 3;
            int ti  = toktmp[tok < cnt1 ? tok : cnt1 - 1];
            const float* xp = x + (size_t)ti * NHID + s * 32 + qq * 8;
            float4 a0 = *(const float4*)xp, a1 = *(const float4*)(xp + 4);
            bf16x8 hh, ll; cvt8(a0, a1, hh, ll);
            char* ab = (char*)Afrag + tok * 2048 + s * 128;
            *(bf16x8*)(ab + (((qq * 2    ) ^ (tok & 7)) << 4)) = hh;
            *(bf16x8*)(ab + (((qq * 2 + 1) ^ (tok & 7)) << 4)) = ll;
        }
    }
    __syncthreads();

    // ================= p_words: register-burst panels ========================
    if (cnt) {
        const int np = h ? 6 : 7;
        for (int pp = wid; pp < np; pp += 4) {
            const int P  = h * 7 + pp;
            const int r  = P * 16 + n;
            const int rr = r < CHUNK ? r : CHUNK - 1;
            const float* wrow = Ww + ((size_t)c * CHUNK + rr) * NHID + q * 8;

            // ---- 32-load burst: whole 32 KB wave-panel into VGPRs ----
            float4 breg[32];
            #pragma unroll
            for (int s = 0; s < 16; ++s) {
                breg[2*s]   = *(const float4*)(wrow + s * 32);
                breg[2*s+1] = *(const float4*)(wrow + s * 32 + 4);
            }
            float bias = bw[c * CHUNK + rr];
            __builtin_amdgcn_sched_barrier(0);   // pin: no load sinks past here

            f32x4 acc = {0.f, 0.f, 0.f, 0.f};
            #pragma unroll
            for (int s = 0; s < 16; ++s) {       // consume in issue order
                const char* ab = (const char*)Afrag + n * 2048 + s * 128;
                bf16x8 ah = *(const bf16x8*)(ab + (((q*2    ) ^ (n&7)) << 4));
                bf16x8 al = *(const bf16x8*)(ab + (((q*2 + 1) ^ (n&7)) << 4));
                bf16x8 bh, bl; cvt8(breg[2*s], breg[2*s+1], bh, bl);
                acc = MFMA(ah, bh, acc);
                acc = MFMA(al, bh, acc);
                acc = MFMA(ah, bl, acc);
            }

            if (r < CHUNK) {
                #pragma unroll
                for (int i = 0; i < 4; ++i)
                    if (msk[i])
                        out[(size_t)tkS[i] * NOUT + NCLS + r] = acc[i] + bias;
            }
        }
    }

    // ================= p_class tail: unit split across 4 waves x 2 ==========
    {
        int unit = -1;
        if (h == 0)          unit = c;
        else if (c < 6)      unit = NCLS + c;     // units 250..255
        if (unit >= 0) {
            class_unit(unit, wid,     lane, n, q, x, Wc, bc, out);
            class_unit(unit, 4 + wid, lane, n, q, x, Wc, bc, out);
        }
    }

    // ============ rare overflow (cnt>16): scalar-FMA residual tail ==========
    if (h == 0 && cnt > 16) {
        const int cw = cnt < MAXTOK ? cnt : MAXTOK;
        const int ov = cw - 16;
        for (int j = tid; j < ov * CHUNK; j += NTHR) {
            const int g  = j / CHUNK;
            const int rr = j - g * CHUNK;
            const int ti = toktmp[16 + g];
            const float4* wr = (const float4*)(Ww + ((size_t)c * CHUNK + rr) * NHID);
            const float4* xr = (const float4*)(x + (size_t)ti * NHID);
            float s0 = 0.f, s1 = 0.f, s2 = 0.f, s3 = 0.f;
            #pragma unroll 4
            for (int k = 0; k < 128; ++k) {
                float4 a = wr[k], b = xr[k];
                s0 += a.x * b.x; s1 += a.y * b.y;
                s2 += a.z * b.z; s3 += a.w * b.w;
            }
            out[(size_t)ti * NOUT + NCLS + rr] =
                (s0 + s1) + (s2 + s3) + bw[c * CHUNK + rr];
        }
    }
}

extern "C" void kernel_launch(void* const* d_in, const int* in_sizes, int n_in,
                              void* d_out, int out_size, void* d_ws, size_t ws_size,
                              hipStream_t stream) {
    const float* x   = (const float*)d_in[0];
    const float* Wc  = (const float*)d_in[1];
    const float* bc  = (const float*)d_in[2];
    const float* Ww  = (const float*)d_in[3];
    const float* bw  = (const float*)d_in[4];
    const int*   cls = (const int*)d_in[5];
    float* out = (float*)d_out;
    hipLaunchKernelGGL(cbd_fused, dim3(NBLK), dim3(NTHR), 0, stream,
                       x, Wc, bc, Ww, bw, cls, out);
}

// Round 7
// 206.257 us; speedup vs baseline: 1.0027x; 1.0027x over previous
//
#include <hip/hip_runtime.h>

#define NHID   512
#define NCLS   250
#define CHUNK  200
#define NTOK   2048
#define NOUT   450
#define NBLK   500             // 2 blocks per class (panels 0-6 / 7-12)
#define NTHR   256             // 4 waves; 2 blocks/CU -> 8 waves/CU
#define MAXTOK 64

typedef __attribute__((ext_vector_type(8))) short bf16x8;
typedef __attribute__((ext_vector_type(4))) float f32x4;

#define MFMA(a, b, c) __builtin_amdgcn_mfma_f32_16x16x32_bf16((a), (b), (c), 0, 0, 0)

__device__ __forceinline__ unsigned hpack(unsigned a, unsigned b) {
    return __builtin_amdgcn_perm(a, b, 0x07060302u);
}

// fp32x8 -> hi/lo split bf16x8 (truncate hi; lo = truncate(exact residual))
__device__ __forceinline__ void cvt8(f32x4 va, f32x4 vb, bf16x8& h, bf16x8& l) {
    unsigned u0 = __float_as_uint(va[0]), u1 = __float_as_uint(va[1]);
    unsigned u2 = __float_as_uint(va[2]), u3 = __float_as_uint(va[3]);
    unsigned u4 = __float_as_uint(vb[0]), u5 = __float_as_uint(vb[1]);
    unsigned u6 = __float_as_uint(vb[2]), u7 = __float_as_uint(vb[3]);
    union { unsigned w[4]; bf16x8 v; } H, L;
    H.w[0] = hpack(u1, u0); H.w[1] = hpack(u3, u2);
    H.w[2] = hpack(u5, u4); H.w[3] = hpack(u7, u6);
    float r0 = va[0] - __uint_as_float(u0 & 0xffff0000u);
    float r1 = va[1] - __uint_as_float(u1 & 0xffff0000u);
    float r2 = va[2] - __uint_as_float(u2 & 0xffff0000u);
    float r3 = va[3] - __uint_as_float(u3 & 0xffff0000u);
    float r4 = vb[0] - __uint_as_float(u4 & 0xffff0000u);
    float r5 = vb[1] - __uint_as_float(u5 & 0xffff0000u);
    float r6 = vb[2] - __uint_as_float(u6 & 0xffff0000u);
    float r7 = vb[3] - __uint_as_float(u7 & 0xffff0000u);
    L.w[0] = hpack(__float_as_uint(r1), __float_as_uint(r0));
    L.w[1] = hpack(__float_as_uint(r3), __float_as_uint(r2));
    L.w[2] = hpack(__float_as_uint(r5), __float_as_uint(r4));
    L.w[3] = hpack(__float_as_uint(r7), __float_as_uint(r6));
    h = H.v; l = L.v;
}

// ---- forced-depth burst machinery (opaque to the compiler scheduler) ----
#define WAITVM(nn) asm volatile("s_waitcnt vmcnt(" #nn ")" ::: "memory")
#define BL(k, off) asm volatile("global_load_dwordx4 %0, %1, off offset:%c2" \
        : "=v"(bv[k]) : "v"(wrow8), "i"(off))
#define BL2(s) BL(2*(s), (s)*128); BL(2*(s)+1, (s)*128 + 16)

#define KSTEP(s) { \
    const char* ab_ = (const char*)Afrag + n * 2048 + (s) * 128; \
    bf16x8 ah_ = *(const bf16x8*)(ab_ + (((q*2    ) ^ (n&7)) << 4)); \
    bf16x8 al_ = *(const bf16x8*)(ab_ + (((q*2 + 1) ^ (n&7)) << 4)); \
    bf16x8 bh_, bl_; cvt8(bv[2*(s)], bv[2*(s)+1], bh_, bl_); \
    acc = MFMA(ah_, bh_, acc); \
    acc = MFMA(al_, bh_, acc); \
    acc = MFMA(ah_, bl_, acc); }

// one column-group (of 8) of a p_class unit, 2-deep register pipeline
__device__ __forceinline__ void class_unit(int u, int w8, int lane, int n, int q,
                                           const float* __restrict__ x,
                                           const float* __restrict__ Wc,
                                           const float* __restrict__ bc,
                                           float* __restrict__ out) {
    const int mt = u >> 1, hn = u & 1;
    const int g4 = (w8 >> 2) & 1, kk = w8 & 3;
    const int rC = (hn * 8 + g4 * 4 + kk) * 16 + n;
    const bool rv = rC < NCLS;
    const int  rc = rv ? rC : NCLS - 1;
    const float* ap = x  + (size_t)(mt * 16 + n) * NHID + q * 8;
    const float* bp = Wc + (size_t)rc * NHID + q * 8;
    const float bias = bc[rc];
    f32x4 acc = {0.f, 0.f, 0.f, 0.f};
    f32x4 qa[2][2], qb[2][2];
    #pragma unroll
    for (int j = 0; j < 2; ++j) {
        qa[j][0] = *(const f32x4*)(ap + j * 32);
        qa[j][1] = *(const f32x4*)(ap + j * 32 + 4);
        qb[j][0] = *(const f32x4*)(bp + j * 32);
        qb[j][1] = *(const f32x4*)(bp + j * 32 + 4);
    }
    #pragma unroll 2
    for (int s = 0; s < 16; ++s) {
        const int b = s & 1;
        bf16x8 ah, al, bh, bl;
        cvt8(qa[b][0], qa[b][1], ah, al);
        cvt8(qb[b][0], qb[b][1], bh, bl);
        acc = MFMA(ah, bh, acc);
        acc = MFMA(al, bh, acc);
        acc = MFMA(ah, bl, acc);
        if (s + 2 < 16) {
            qa[b][0] = *(const f32x4*)(ap + (s + 2) * 32);
            qa[b][1] = *(const f32x4*)(ap + (s + 2) * 32 + 4);
            qb[b][0] = *(const f32x4*)(bp + (s + 2) * 32);
            qb[b][1] = *(const f32x4*)(bp + (s + 2) * 32 + 4);
        }
    }
    if (rv) {
        #pragma unroll
        for (int i = 0; i < 4; ++i)
            out[(size_t)(mt * 16 + q * 4 + i) * NOUT + rc] = acc[i] + bias;
    }
}

__global__ __launch_bounds__(NTHR, 2)
void cbd_fused(const float* __restrict__ x,  const float* __restrict__ Wc,
               const float* __restrict__ bc, const float* __restrict__ Ww,
               const float* __restrict__ bw, const int* __restrict__ cls_idx,
               float* __restrict__ out)
{
    __shared__ short Afrag[16384];   // 16 tok x 16 ks x 4 q x (ah|al), 32 KB
    __shared__ int   toktmp[MAXTOK];

    const int tid  = threadIdx.x;
    const int wid  = tid >> 6;        // 0..3
    const int lane = tid & 63;
    const int n    = lane & 15;
    const int q    = lane >> 4;
    const int c    = blockIdx.x >> 1; // class
    const int h    = blockIdx.x & 1;  // panel half: 0 -> 0..6, 1 -> 7..12

    // ---- per-wave redundant token scan (identical values per wave) ----
    int myvals[32];
    #pragma unroll
    for (int it = 0; it < 8; ++it) {
        int4 v = *(const int4*)&cls_idx[it * 256 + lane * 4];
        myvals[it*4+0] = v.x; myvals[it*4+1] = v.y;
        myvals[it*4+2] = v.z; myvals[it*4+3] = v.w;
    }
    int cnt = 0;
    #pragma unroll
    for (int j = 0; j < 32; ++j) {
        int idx  = (j >> 2) * 256 + lane * 4 + (j & 3);
        bool hit = (myvals[j] == c);
        unsigned long long m = __ballot(hit);
        if (hit) {
            int pos = cnt + (int)__popcll(m & ((1ull << lane) - 1ull));
            if (pos < MAXTOK) toktmp[pos] = idx;
        }
        cnt += (int)__popcll(m);
    }
    const int cnt1 = cnt < 16 ? cnt : 16;

    int tkS[4]; bool msk[4];
    if (cnt) {
        int mytokA = toktmp[n < cnt1 ? n : cnt1 - 1];
        #pragma unroll
        for (int i = 0; i < 4; ++i) {
            tkS[i] = __shfl(mytokA, q * 4 + i);
            msk[i] = (q * 4 + i) < cnt1;
        }
        // ---- stage A once: split-bf16 fragments, XOR-swizzled slots ----
        #pragma unroll
        for (int rep = 0; rep < 4; ++rep) {
            int job = rep * 256 + tid;
            int tok = job >> 6, s = (job >> 2) & 15, qq = job & 3;
            int ti  = toktmp[tok < cnt1 ? tok : cnt1 - 1];
            const float* xp = x + (size_t)ti * NHID + s * 32 + qq * 8;
            f32x4 a0 = *(const f32x4*)xp, a1 = *(const f32x4*)(xp + 4);
            bf16x8 hh, ll; cvt8(a0, a1, hh, ll);
            char* ab = (char*)Afrag + tok * 2048 + s * 128;
            *(bf16x8*)(ab + (((qq * 2    ) ^ (tok & 7)) << 4)) = hh;
            *(bf16x8*)(ab + (((qq * 2 + 1) ^ (tok & 7)) << 4)) = ll;
        }
    }
    __syncthreads();

    // ================= p_words: inline-asm burst panels =====================
    if (cnt) {
        const int np = h ? 6 : 7;
        for (int pp = wid; pp < np; pp += 4) {
            const int P  = h * 7 + pp;
            const int r  = P * 16 + n;
            const int rr = r < CHUNK ? r : CHUNK - 1;
            const char* wrow8 =
                (const char*)(Ww + ((size_t)c * CHUNK + rr) * NHID + q * 8);
            float bias = bw[c * CHUNK + rr];

            // clean vmcnt base (drains bias + previous panel's stores)
            WAITVM(0);
            __builtin_amdgcn_sched_barrier(0);

            // ---- forced 32-load burst: 32 KB/wave genuinely in flight ----
            f32x4 bv[32];
            BL2(0);  BL2(1);  BL2(2);  BL2(3);
            BL2(4);  BL2(5);  BL2(6);  BL2(7);
            BL2(8);  BL2(9);  BL2(10); BL2(11);
            BL2(12); BL2(13); BL2(14); BL2(15);

            f32x4 acc = {0.f, 0.f, 0.f, 0.f};
            WAITVM(24); __builtin_amdgcn_sched_barrier(0);
            KSTEP(0)  KSTEP(1)  KSTEP(2)  KSTEP(3)
            WAITVM(16); __builtin_amdgcn_sched_barrier(0);
            KSTEP(4)  KSTEP(5)  KSTEP(6)  KSTEP(7)
            WAITVM(8);  __builtin_amdgcn_sched_barrier(0);
            KSTEP(8)  KSTEP(9)  KSTEP(10) KSTEP(11)
            WAITVM(0);  __builtin_amdgcn_sched_barrier(0);
            KSTEP(12) KSTEP(13) KSTEP(14) KSTEP(15)

            if (r < CHUNK) {
                #pragma unroll
                for (int i = 0; i < 4; ++i)
                    if (msk[i])
                        out[(size_t)tkS[i] * NOUT + NCLS + r] = acc[i] + bias;
            }
        }
    }

    // ================= p_class tail: unit split across 4 waves x 2 ==========
    {
        int unit = -1;
        if (h == 0)          unit = c;
        else if (c < 6)      unit = NCLS + c;     // units 250..255
        if (unit >= 0) {
            class_unit(unit, wid,     lane, n, q, x, Wc, bc, out);
            class_unit(unit, 4 + wid, lane, n, q, x, Wc, bc, out);
        }
    }

    // ============ rare overflow (cnt>16): scalar-FMA residual tail ==========
    if (h == 0 && cnt > 16) {
        const int cw = cnt < MAXTOK ? cnt : MAXTOK;
        const int ov = cw - 16;
        for (int j = tid; j < ov * CHUNK; j += NTHR) {
            const int g  = j / CHUNK;
            const int rr = j - g * CHUNK;
            const int ti = toktmp[16 + g];
            const float4* wr = (const float4*)(Ww + ((size_t)c * CHUNK + rr) * NHID);
            const float4* xr = (const float4*)(x + (size_t)ti * NHID);
            float s0 = 0.f, s1 = 0.f, s2 = 0.f, s3 = 0.f;
            #pragma unroll 4
            for (int k = 0; k < 128; ++k) {
                float4 a = wr[k], b = xr[k];
                s0 += a.x * b.x; s1 += a.y * b.y;
                s2 += a.z * b.z; s3 += a.w * b.w;
            }
            out[(size_t)ti * NOUT + NCLS + rr] =
                (s0 + s1) + (s2 + s3) + bw[c * CHUNK + rr];
        }
    }
}

extern "C" void kernel_launch(void* const* d_in, const int* in_sizes, int n_in,
                              void* d_out, int out_size, void* d_ws, size_t ws_size,
                              hipStream_t stream) {
    const float* x   = (const float*)d_in[0];
    const float* Wc  = (const float*)d_in[1];
    const float* bc  = (const float*)d_in[2];
    const float* Ww  = (const float*)d_in[3];
    const float* bw  = (const float*)d_in[4];
    const int*   cls = (const int*)d_in[5];
    float* out = (float*)d_out;
    hipLaunchKernelGGL(cbd_fused, dim3(NBLK), dim3(NTHR), 0, stream,
                       x, Wc, bc, Ww, bw, cls, out);
}